// Round 3
// baseline (336.272 us; speedup 1.0000x reference)
//
#include <hip/hip_runtime.h>
#include <hip/hip_bf16.h>

// 3-layer tanh RNN. B=32, T=64, D_IN=10000, H=200, N_CLASSES=2.
//
// R10:
//  * rec SPILL FIX (the real one): R8 (VGPR=80, w[4][28]) and R9 (VGPR=52,
//    w[2][40]) both ran 66.4us/step-chain == 160KB/step scratch reload at
//    L1 BW (~2560cy/step, measured 2490). Local ARRAYS lose regalloc under
//    divergent guards regardless of static indexing. Fix: 20 NAMED float4
//    variables for w (nothing to demote), dot-chains split into 2 halves.
//    Expected signature: VGPR ~110-130, rec 66 -> ~25us.
//  * launch structure from R9 kept: pack_all single launch; partial-reduce
//    folded into rec L0 staging; fc head folded into rec L2.
//  * gemm: R8's BM=64 / 2-blocks-per-CU version retained unchanged.
//  * split-bf16 3-term everywhere: ~fp32 accuracy at bf16 MFMA rate.

typedef __bf16  bf16x8 __attribute__((ext_vector_type(8)));
typedef __bf16  bf16x4 __attribute__((ext_vector_type(4)));
typedef float   f32x4  __attribute__((ext_vector_type(4)));

#define HDIM 200
#define BM 64
#define CHUNK_B 26624   // bytes per packed k-chunk: [208x32] hi (13312) + lo
#define MFMA(a, b, c) __builtin_amdgcn_mfma_f32_16x16x32_bf16(a, b, c, 0, 0, 0)

__device__ __forceinline__ void glds16(const void* g, void* l) {
    __builtin_amdgcn_global_load_lds(
        (const __attribute__((address_space(1))) unsigned int*)g,
        (__attribute__((address_space(3))) unsigned int*)l, 16, 0, 0);
}

// ---- pack W [HDIM x K] fp32 -> chunks: [kc][208 rows x 32 k] bf16 hi, lo ----
// One launch packs all three W_ih weights (W0 dominates: 320 of 334 chunks).
__global__ void pack_all(const float* __restrict__ W0,
                         const float* __restrict__ W1,
                         const float* __restrict__ W2,
                         __bf16* __restrict__ O0,
                         __bf16* __restrict__ O1,
                         __bf16* __restrict__ O2)
{
    const int T0 = 320 * 1664, T1 = 7 * 1664, T2 = 7 * 1664;
    for (int gt = blockIdx.x * blockDim.x + threadIdx.x; gt < T0 + T1 + T2;
         gt += gridDim.x * blockDim.x) {
        const float* W; __bf16* out; int K, g;
        if (gt < T0)           { W = W0; out = O0; K = 10000; g = gt; }
        else if (gt < T0 + T1) { W = W1; out = O1; K = HDIM;  g = gt - T0; }
        else                   { W = W2; out = O2; K = HDIM;  g = gt - T0 - T1; }

        const int kc = g / 1664;
        const int o  = g - kc * 1664;
        const int isLo = (o >= 832);
        const int o2 = isLo ? o - 832 : o;
        const int r  = o2 >> 2;              // 0..207
        const int k  = kc * 32 + (o2 & 3) * 8;
        bf16x8 v;
        if (r < HDIM && k < K) {             // K % 8 == 0
            const float* p = W + (size_t)r * K + k;
            float4 a = *(const float4*)p, b = *(const float4*)(p + 4);
            float f[8] = {a.x, a.y, a.z, a.w, b.x, b.y, b.z, b.w};
#pragma unroll
            for (int i = 0; i < 8; ++i) {
                __bf16 h = (__bf16)f[i];
                v[i] = isLo ? (__bf16)(f[i] - (float)h) : h;
            }
        } else {
#pragma unroll
            for (int i = 0; i < 8; ++i) v[i] = (__bf16)0.f;
        }
        *(bf16x8*)&out[(size_t)g * 8] = v;
    }
}

// ---- pipelined GEMM: C[m][n] = sum_k A[m][k]*W[n][k] over this block's k ----
// BM=64 (4 Mtiles). 8 waves = 2 M-groups (2 Mtiles each) x 4 N-groups
// (4/3/3/3 ntiles). One barrier/kstep. 68 KB LDS -> 2 blocks/CU.
__global__ __launch_bounds__(512, 4)
void gemm_pipe(const float* __restrict__ A, int lda, int K,
               const __bf16* __restrict__ Bpack,
               float* __restrict__ Cbase, int per_split, int ksteps)
{
    __shared__ alignas(16) __bf16 Ab[2][4096];    // [hi 2048 | lo 2048] (64x32)
    __shared__ alignas(16) __bf16 Bb[2][13312];   // [hi 6656 | lo 6656] (208x32)

    const int tid = threadIdx.x;
    const int kc0 = blockIdx.y * ksteps;
    const int m0  = blockIdx.x * BM;
    float* __restrict__ C = Cbase + (size_t)blockIdx.y * per_split;

    const int wv = tid >> 6, lane = tid & 63;
    const int r16 = lane & 15, kg = lane >> 4;
    const int mg = wv & 1, ng = wv >> 1;
    const int nt0 = ng ? 1 + ng * 3 : 0;        // 0,4,7,10
    const int ntw = ng ? 3 : 4;

    const int a_row = tid >> 3;          // 0..63
    const int a_q   = tid & 7;           // float4 column group
    const float* Arow = A + (size_t)(m0 + a_row) * lda + a_q * 4;

    f32x4 acc[2][4];
#pragma unroll
    for (int mi = 0; mi < 2; ++mi)
#pragma unroll
        for (int j = 0; j < 4; ++j) acc[mi][j] = (f32x4)0.f;

    float av[4];
    auto loadA = [&](int ks) {
        const int kb = (kc0 + ks) * 32;
        if (kb + a_q * 4 < K) {          // 4-granular, K % 4 == 0
            float4 x0 = *(const float4*)(Arow + kb);
            av[0] = x0.x; av[1] = x0.y; av[2] = x0.z; av[3] = x0.w;
        } else {
#pragma unroll
            for (int i = 0; i < 4; ++i) av[i] = 0.f;
        }
    };
    auto issueB = [&](int ks, int buf) {
        const char* src = (const char*)Bpack + (size_t)(kc0 + ks) * CHUNK_B;
        char* dst = (char*)&Bb[buf][0];
#pragma unroll
        for (int r = 0; r < 3; ++r)
            glds16(src + (r * 512 + tid) * 16, dst + (r * 512 + tid) * 16);
        if (tid < 128)
            glds16(src + (1536 + tid) * 16, dst + (1536 + tid) * 16);
    };

    loadA(0);
    issueB(0, 0);

    for (int ks = 0; ks < ksteps; ++ks) {
        const int cur = ks & 1, nxt = cur ^ 1;
        // commit A regs -> LDS hi/lo  (Ab[cur] last read in iter ks-2: safe)
        bf16x4 th, tl;
#pragma unroll
        for (int i = 0; i < 4; ++i) {
            __bf16 h = (__bf16)av[i];
            th[i] = h; tl[i] = (__bf16)(av[i] - (float)h);
        }
        *(bf16x4*)&Ab[cur][a_row * 32 + a_q * 4]        = th;
        *(bf16x4*)&Ab[cur][2048 + a_row * 32 + a_q * 4] = tl;
        __syncthreads();   // drains glds B(ks)->Bb[cur] + A writes (vmcnt+lgkm)
        if (ks + 1 < ksteps) { issueB(ks + 1, nxt); loadA(ks + 1); }

        const int ao0 = (mg * 32 + r16) * 32 + kg * 8;
        const int ao1 = ao0 + 16 * 32;
        bf16x8 ah0 = *(const bf16x8*)&Ab[cur][ao0];
        bf16x8 al0 = *(const bf16x8*)&Ab[cur][2048 + ao0];
        bf16x8 ah1 = *(const bf16x8*)&Ab[cur][ao1];
        bf16x8 al1 = *(const bf16x8*)&Ab[cur][2048 + ao1];
#pragma unroll
        for (int j = 0; j < 4; ++j) {
            if (j < ntw) {
                const int bo = ((nt0 + j) * 16 + r16) * 32 + kg * 8;
                bf16x8 bh = *(const bf16x8*)&Bb[cur][bo];
                bf16x8 bl = *(const bf16x8*)&Bb[cur][6656 + bo];
                acc[0][j] = MFMA(al0, bh, acc[0][j]);
                acc[0][j] = MFMA(ah0, bl, acc[0][j]);
                acc[0][j] = MFMA(ah0, bh, acc[0][j]);
                acc[1][j] = MFMA(al1, bh, acc[1][j]);
                acc[1][j] = MFMA(ah1, bl, acc[1][j]);
                acc[1][j] = MFMA(ah1, bh, acc[1][j]);
            }
        }
    }

    // epilogue: C/D layout col=lane&15, row=(lane>>4)*4+reg; plain stores
#pragma unroll
    for (int mi = 0; mi < 2; ++mi) {
        const int rb = m0 + mg * 32 + mi * 16 + kg * 4;
#pragma unroll
        for (int j = 0; j < 4; ++j) {
            if (j < ntw) {
                const int n = (nt0 + j) * 16 + r16;
                if (n < HDIM)
#pragma unroll
                    for (int r = 0; r < 4; ++r)
                        C[(size_t)(rb + r) * HDIM + n] = acc[mi][j][r];
            }
        }
    }
}

__device__ __forceinline__ float fast_tanh(float x) {
    float e = __expf(-2.f * fabsf(x));
    float r = (1.f - e) / (1.f + e);
    return copysignf(r, x);
}

// ---- recurrence: 1 block/batch; thread owns 2 n x 40 k; w in 20 NAMED
// float4 VGPRs (arrays spill -- R8/R9 lesson). 5-way k-split, part[] LDS
// reduce, 2 barriers/step. Prologue sums nparts k-split GEMM partials into
// preS. Optional fused FC head for the last layer. ----
__global__ __launch_bounds__(512, 1)
void rnn_rec(const float* __restrict__ pre,   // [nparts][32][64][200] partials
             int nparts, int pstride,          // floats between partials
             const float* __restrict__ Whh,   // [200][200]
             const float* __restrict__ bih,
             const float* __restrict__ bhh,
             float* __restrict__ Hout,        // [32][64][200]
             const float* __restrict__ fcw,   // [2][200] or nullptr
             const float* __restrict__ fcb,
             float* __restrict__ outp)        // [32][2]
{
    const int b   = blockIdx.x;
    const int tid = threadIdx.x;

    __shared__ float preS[64 * HDIM];          // 51.2 KB
    __shared__ float h[HDIM];
    __shared__ float bias[HDIM];
    __shared__ float part[5][HDIM];            // 4 KB

    {   // stage pre slab, summing k-split partials (coalesced)
        const float4* ps = (const float4*)(pre + (size_t)b * 64 * HDIM);
        float4* pd = (float4*)preS;
        const size_t pq = (size_t)pstride / 4;      // float4 stride
        for (int i = tid; i < 3200; i += 512) {
            float4 s = ps[i];
            for (int r = 1; r < nparts; ++r) {
                float4 v = ps[(size_t)r * pq + i];
                s.x += v.x; s.y += v.y; s.z += v.z; s.w += v.w;
            }
            pd[i] = s;
        }
    }

    const bool act = tid < 500;
    const int g  = tid / 5;             // n-group 0..99 (div: setup only)
    const int s5 = tid - g * 5;         // k-slice 0..4
    const int n0 = g * 2;
    const int k0 = s5 * 40;

    // 20 named float4s: w0_* = row n0, w1_* = row n0+1, each 40 k wide.
    float4 w0_0, w0_1, w0_2, w0_3, w0_4, w0_5, w0_6, w0_7, w0_8, w0_9;
    float4 w1_0, w1_1, w1_2, w1_3, w1_4, w1_5, w1_6, w1_7, w1_8, w1_9;
    if (act) {
        const float* wr0 = Whh + (size_t)n0 * HDIM + k0;
        const float* wr1 = wr0 + HDIM;
        w0_0 = *(const float4*)(wr0 +  0); w0_1 = *(const float4*)(wr0 +  4);
        w0_2 = *(const float4*)(wr0 +  8); w0_3 = *(const float4*)(wr0 + 12);
        w0_4 = *(const float4*)(wr0 + 16); w0_5 = *(const float4*)(wr0 + 20);
        w0_6 = *(const float4*)(wr0 + 24); w0_7 = *(const float4*)(wr0 + 28);
        w0_8 = *(const float4*)(wr0 + 32); w0_9 = *(const float4*)(wr0 + 36);
        w1_0 = *(const float4*)(wr1 +  0); w1_1 = *(const float4*)(wr1 +  4);
        w1_2 = *(const float4*)(wr1 +  8); w1_3 = *(const float4*)(wr1 + 12);
        w1_4 = *(const float4*)(wr1 + 16); w1_5 = *(const float4*)(wr1 + 20);
        w1_6 = *(const float4*)(wr1 + 24); w1_7 = *(const float4*)(wr1 + 28);
        w1_8 = *(const float4*)(wr1 + 32); w1_9 = *(const float4*)(wr1 + 36);
    }
    if (tid < HDIM) { bias[tid] = bih[tid] + bhh[tid]; h[tid] = 0.f; }
    __syncthreads();

#define DOT4(wv, hv) ((wv).x*(hv).x + (wv).y*(hv).y + (wv).z*(hv).z + (wv).w*(hv).w)

    for (int t = 0; t < 64; ++t) {
        if (act) {
            const float4 hv0 = *(const float4*)&h[k0 +  0];
            const float4 hv1 = *(const float4*)&h[k0 +  4];
            const float4 hv2 = *(const float4*)&h[k0 +  8];
            const float4 hv3 = *(const float4*)&h[k0 + 12];
            const float4 hv4 = *(const float4*)&h[k0 + 16];
            const float4 hv5 = *(const float4*)&h[k0 + 20];
            const float4 hv6 = *(const float4*)&h[k0 + 24];
            const float4 hv7 = *(const float4*)&h[k0 + 28];
            const float4 hv8 = *(const float4*)&h[k0 + 32];
            const float4 hv9 = *(const float4*)&h[k0 + 36];
            // two-accumulator halves to break the 40-FMA dependency chain
            float a0 = (DOT4(w0_0,hv0)+DOT4(w0_1,hv1)+DOT4(w0_2,hv2)+DOT4(w0_3,hv3)+DOT4(w0_4,hv4))
                     + (DOT4(w0_5,hv5)+DOT4(w0_6,hv6)+DOT4(w0_7,hv7)+DOT4(w0_8,hv8)+DOT4(w0_9,hv9));
            float a1 = (DOT4(w1_0,hv0)+DOT4(w1_1,hv1)+DOT4(w1_2,hv2)+DOT4(w1_3,hv3)+DOT4(w1_4,hv4))
                     + (DOT4(w1_5,hv5)+DOT4(w1_6,hv6)+DOT4(w1_7,hv7)+DOT4(w1_8,hv8)+DOT4(w1_9,hv9));
            *(float2*)&part[s5][n0] = make_float2(a0, a1);
        }
        __syncthreads();   // part ready; h no longer read this step
        if (tid < HDIM) {
            float sum = part[0][tid] + part[1][tid] + part[2][tid]
                      + part[3][tid] + part[4][tid];
            float v = fast_tanh(sum + preS[t * HDIM + tid] + bias[tid]);
            h[tid] = v;
            Hout[((size_t)b * 64 + t) * HDIM + tid] = v;
        }
        __syncthreads();   // h ready for step t+1; part free for rewrite
    }

    // fused FC head (last layer only): h == h_63 in LDS
    if (fcw != nullptr && tid < 16) {
        const int cls = tid & 1, sl = tid >> 1;      // 8 slices of 25
        const float* fw = fcw + cls * HDIM + sl * 25;
        const float* hp = h + sl * 25;
        float sacc = 0.f;
#pragma unroll
        for (int j = 0; j < 25; ++j) sacc += hp[j] * fw[j];
        sacc += __shfl_xor(sacc, 2);
        sacc += __shfl_xor(sacc, 4);
        sacc += __shfl_xor(sacc, 8);
        if (sl == 0) outp[b * 2 + cls] = sacc + fcb[cls];
    }
}

extern "C" void kernel_launch(void* const* d_in, const int* in_sizes, int n_in,
                              void* d_out, int out_size, void* d_ws, size_t ws_size,
                              hipStream_t stream) {
    const float* x     = (const float*)d_in[0];
    const float* W_ih0 = (const float*)d_in[1];
    const float* W_hh0 = (const float*)d_in[2];
    const float* b_ih0 = (const float*)d_in[3];
    const float* b_hh0 = (const float*)d_in[4];
    const float* W_ih1 = (const float*)d_in[5];
    const float* W_hh1 = (const float*)d_in[6];
    const float* b_ih1 = (const float*)d_in[7];
    const float* b_hh1 = (const float*)d_in[8];
    const float* W_ih2 = (const float*)d_in[9];
    const float* W_hh2 = (const float*)d_in[10];
    const float* b_ih2 = (const float*)d_in[11];
    const float* b_hh2 = (const float*)d_in[12];
    const float* fc_w  = (const float*)d_in[13];
    const float* fc_b  = (const float*)d_in[14];
    float* out = (float*)d_out;

    const size_t PE = (size_t)2048 * HDIM;          // 409600
    float* P     = (float*)d_ws;
    float* Hbuf  = P + PE;
    float* Hbuf2 = Hbuf + PE;
    float* Ppart = Hbuf2 + PE;                      // 16 x 409600
    __bf16* W0p  = (__bf16*)(Ppart + 16 * PE);      // 320 chunks x 13312 bf16
    __bf16* W1p  = W0p + (size_t)320 * 13312;       // 7 chunks
    __bf16* W2p  = W1p + (size_t)7 * 13312;
    // total ws: ~40.0 MB

    // ---- prologue: pack all weights (one launch) ----
    pack_all<<<1024, 256, 0, stream>>>(W_ih0, W_ih1, W_ih2, W0p, W1p, W2p);

    // ---- layer 0: K=10000, 16-way k-split (20 ksteps each); partials are
    //      reduced inside rnn_rec's staging ----
    gemm_pipe<<<dim3(32, 16), 512, 0, stream>>>(x, 10000, 10000, W0p, Ppart, (int)PE, 20);
    rnn_rec<<<32, 512, 0, stream>>>(Ppart, 16, (int)PE, W_hh0, b_ih0, b_hh0,
                                    Hbuf, nullptr, nullptr, nullptr);

    // ---- layer 1: K=200, single split, direct store ----
    gemm_pipe<<<dim3(32, 1), 512, 0, stream>>>(Hbuf, HDIM, HDIM, W1p, P, (int)PE, 7);
    rnn_rec<<<32, 512, 0, stream>>>(P, 1, (int)PE, W_hh1, b_ih1, b_hh1,
                                    Hbuf2, nullptr, nullptr, nullptr);

    // ---- layer 2 + fused FC head ----
    gemm_pipe<<<dim3(32, 1), 512, 0, stream>>>(Hbuf2, HDIM, HDIM, W2p, P, (int)PE, 7);
    rnn_rec<<<32, 512, 0, stream>>>(P, 1, (int)PE, W_hh2, b_ih2, b_hh2,
                                    Hbuf, fc_w, fc_b, out);
}

// Round 4
// 334.738 us; speedup vs baseline: 1.0046x; 1.0046x over previous
//
#include <hip/hip_runtime.h>
#include <hip/hip_bf16.h>

// 3-layer tanh RNN. B=32, T=64, D_IN=10000, H=200, N_CLASSES=2.
//
// R11:
//  * rec REMAT FIX: R8/R9/R10 all ran ~67us with VGPR=52 -- the compiler
//    REMATERIALIZES the loop-invariant Whh loads inside the loop (legal
//    under __restrict__), i.e. 160KB/step reloads at L1 BW ~= 2500cy/step.
//    Named variables can't stop remat; opaque `asm volatile("" : "+v")`
//    pins can (an asm result can't be rematerialized). 20 PIN4 pins.
//  * rec STORE-DRAIN FIX: Hout store was inside the loop; every
//    __syncthreads() drains vmcnt(0) -> ~300cy global-store ack per step.
//    h_t now overwrites its own consumed preS slot (same-thread RAW, no
//    race); one coalesced bulk store preS->Hout after the loop.
//  * launch structure from R9; gemm from R8 (BM=64, 2 blocks/CU) unchanged.
//  * split-bf16 3-term everywhere: ~fp32 accuracy at bf16 MFMA rate.

typedef __bf16  bf16x8 __attribute__((ext_vector_type(8)));
typedef __bf16  bf16x4 __attribute__((ext_vector_type(4)));
typedef float   f32x4  __attribute__((ext_vector_type(4)));

#define HDIM 200
#define BM 64
#define CHUNK_B 26624   // bytes per packed k-chunk: [208x32] hi (13312) + lo
#define MFMA(a, b, c) __builtin_amdgcn_mfma_f32_16x16x32_bf16(a, b, c, 0, 0, 0)

__device__ __forceinline__ void glds16(const void* g, void* l) {
    __builtin_amdgcn_global_load_lds(
        (const __attribute__((address_space(1))) unsigned int*)g,
        (__attribute__((address_space(3))) unsigned int*)l, 16, 0, 0);
}

// ---- pack W [HDIM x K] fp32 -> chunks: [kc][208 rows x 32 k] bf16 hi, lo ----
// One launch packs all three W_ih weights (W0 dominates: 320 of 334 chunks).
__global__ void pack_all(const float* __restrict__ W0,
                         const float* __restrict__ W1,
                         const float* __restrict__ W2,
                         __bf16* __restrict__ O0,
                         __bf16* __restrict__ O1,
                         __bf16* __restrict__ O2)
{
    const int T0 = 320 * 1664, T1 = 7 * 1664, T2 = 7 * 1664;
    for (int gt = blockIdx.x * blockDim.x + threadIdx.x; gt < T0 + T1 + T2;
         gt += gridDim.x * blockDim.x) {
        const float* W; __bf16* out; int K, g;
        if (gt < T0)           { W = W0; out = O0; K = 10000; g = gt; }
        else if (gt < T0 + T1) { W = W1; out = O1; K = HDIM;  g = gt - T0; }
        else                   { W = W2; out = O2; K = HDIM;  g = gt - T0 - T1; }

        const int kc = g / 1664;
        const int o  = g - kc * 1664;
        const int isLo = (o >= 832);
        const int o2 = isLo ? o - 832 : o;
        const int r  = o2 >> 2;              // 0..207
        const int k  = kc * 32 + (o2 & 3) * 8;
        bf16x8 v;
        if (r < HDIM && k < K) {             // K % 8 == 0
            const float* p = W + (size_t)r * K + k;
            float4 a = *(const float4*)p, b = *(const float4*)(p + 4);
            float f[8] = {a.x, a.y, a.z, a.w, b.x, b.y, b.z, b.w};
#pragma unroll
            for (int i = 0; i < 8; ++i) {
                __bf16 h = (__bf16)f[i];
                v[i] = isLo ? (__bf16)(f[i] - (float)h) : h;
            }
        } else {
#pragma unroll
            for (int i = 0; i < 8; ++i) v[i] = (__bf16)0.f;
        }
        *(bf16x8*)&out[(size_t)g * 8] = v;
    }
}

// ---- pipelined GEMM: C[m][n] = sum_k A[m][k]*W[n][k] over this block's k ----
// BM=64 (4 Mtiles). 8 waves = 2 M-groups (2 Mtiles each) x 4 N-groups
// (4/3/3/3 ntiles). One barrier/kstep. 68 KB LDS -> 2 blocks/CU.
__global__ __launch_bounds__(512, 4)
void gemm_pipe(const float* __restrict__ A, int lda, int K,
               const __bf16* __restrict__ Bpack,
               float* __restrict__ Cbase, int per_split, int ksteps)
{
    __shared__ alignas(16) __bf16 Ab[2][4096];    // [hi 2048 | lo 2048] (64x32)
    __shared__ alignas(16) __bf16 Bb[2][13312];   // [hi 6656 | lo 6656] (208x32)

    const int tid = threadIdx.x;
    const int kc0 = blockIdx.y * ksteps;
    const int m0  = blockIdx.x * BM;
    float* __restrict__ C = Cbase + (size_t)blockIdx.y * per_split;

    const int wv = tid >> 6, lane = tid & 63;
    const int r16 = lane & 15, kg = lane >> 4;
    const int mg = wv & 1, ng = wv >> 1;
    const int nt0 = ng ? 1 + ng * 3 : 0;        // 0,4,7,10
    const int ntw = ng ? 3 : 4;

    const int a_row = tid >> 3;          // 0..63
    const int a_q   = tid & 7;           // float4 column group
    const float* Arow = A + (size_t)(m0 + a_row) * lda + a_q * 4;

    f32x4 acc[2][4];
#pragma unroll
    for (int mi = 0; mi < 2; ++mi)
#pragma unroll
        for (int j = 0; j < 4; ++j) acc[mi][j] = (f32x4)0.f;

    float av[4];
    auto loadA = [&](int ks) {
        const int kb = (kc0 + ks) * 32;
        if (kb + a_q * 4 < K) {          // 4-granular, K % 4 == 0
            float4 x0 = *(const float4*)(Arow + kb);
            av[0] = x0.x; av[1] = x0.y; av[2] = x0.z; av[3] = x0.w;
        } else {
#pragma unroll
            for (int i = 0; i < 4; ++i) av[i] = 0.f;
        }
    };
    auto issueB = [&](int ks, int buf) {
        const char* src = (const char*)Bpack + (size_t)(kc0 + ks) * CHUNK_B;
        char* dst = (char*)&Bb[buf][0];
#pragma unroll
        for (int r = 0; r < 3; ++r)
            glds16(src + (r * 512 + tid) * 16, dst + (r * 512 + tid) * 16);
        if (tid < 128)
            glds16(src + (1536 + tid) * 16, dst + (1536 + tid) * 16);
    };

    loadA(0);
    issueB(0, 0);

    for (int ks = 0; ks < ksteps; ++ks) {
        const int cur = ks & 1, nxt = cur ^ 1;
        // commit A regs -> LDS hi/lo  (Ab[cur] last read in iter ks-2: safe)
        bf16x4 th, tl;
#pragma unroll
        for (int i = 0; i < 4; ++i) {
            __bf16 h = (__bf16)av[i];
            th[i] = h; tl[i] = (__bf16)(av[i] - (float)h);
        }
        *(bf16x4*)&Ab[cur][a_row * 32 + a_q * 4]        = th;
        *(bf16x4*)&Ab[cur][2048 + a_row * 32 + a_q * 4] = tl;
        __syncthreads();   // drains glds B(ks)->Bb[cur] + A writes (vmcnt+lgkm)
        if (ks + 1 < ksteps) { issueB(ks + 1, nxt); loadA(ks + 1); }

        const int ao0 = (mg * 32 + r16) * 32 + kg * 8;
        const int ao1 = ao0 + 16 * 32;
        bf16x8 ah0 = *(const bf16x8*)&Ab[cur][ao0];
        bf16x8 al0 = *(const bf16x8*)&Ab[cur][2048 + ao0];
        bf16x8 ah1 = *(const bf16x8*)&Ab[cur][ao1];
        bf16x8 al1 = *(const bf16x8*)&Ab[cur][2048 + ao1];
#pragma unroll
        for (int j = 0; j < 4; ++j) {
            if (j < ntw) {
                const int bo = ((nt0 + j) * 16 + r16) * 32 + kg * 8;
                bf16x8 bh = *(const bf16x8*)&Bb[cur][bo];
                bf16x8 bl = *(const bf16x8*)&Bb[cur][6656 + bo];
                acc[0][j] = MFMA(al0, bh, acc[0][j]);
                acc[0][j] = MFMA(ah0, bl, acc[0][j]);
                acc[0][j] = MFMA(ah0, bh, acc[0][j]);
                acc[1][j] = MFMA(al1, bh, acc[1][j]);
                acc[1][j] = MFMA(ah1, bl, acc[1][j]);
                acc[1][j] = MFMA(ah1, bh, acc[1][j]);
            }
        }
    }

    // epilogue: C/D layout col=lane&15, row=(lane>>4)*4+reg; plain stores
#pragma unroll
    for (int mi = 0; mi < 2; ++mi) {
        const int rb = m0 + mg * 32 + mi * 16 + kg * 4;
#pragma unroll
        for (int j = 0; j < 4; ++j) {
            if (j < ntw) {
                const int n = (nt0 + j) * 16 + r16;
                if (n < HDIM)
#pragma unroll
                    for (int r = 0; r < 4; ++r)
                        C[(size_t)(rb + r) * HDIM + n] = acc[mi][j][r];
            }
        }
    }
}

__device__ __forceinline__ float fast_tanh(float x) {
    float e = __expf(-2.f * fabsf(x));
    float r = (1.f - e) / (1.f + e);
    return copysignf(r, x);
}

// opaque pin: value becomes an asm result -> cannot be rematerialized from
// its defining load; must stay live in VGPRs across the loop.
#define PIN4(v) asm volatile("" : "+v"(v.x), "+v"(v.y), "+v"(v.z), "+v"(v.w))

// ---- recurrence: 1 block/batch; thread owns 2 n x 40 k; w pinned into
// VGPRs via opaque asm (remat-proof). 5-way k-split, part[] LDS reduce,
// 2 barriers/step; NO global traffic inside the step loop (h_t overwrites
// its consumed preS slot; bulk Hout store at end). Prologue sums nparts
// k-split GEMM partials into preS. Optional fused FC head. ----
__global__ __launch_bounds__(512, 1)
void rnn_rec(const float* __restrict__ pre,   // [nparts][32][64][200] partials
             int nparts, int pstride,          // floats between partials
             const float* __restrict__ Whh,   // [200][200]
             const float* __restrict__ bih,
             const float* __restrict__ bhh,
             float* __restrict__ Hout,        // [32][64][200]
             const float* __restrict__ fcw,   // [2][200] or nullptr
             const float* __restrict__ fcb,
             float* __restrict__ outp)        // [32][2]
{
    const int b   = blockIdx.x;
    const int tid = threadIdx.x;

    __shared__ float preS[64 * HDIM];          // 51.2 KB; pre in, h out
    __shared__ float h[HDIM];
    __shared__ float bias[HDIM];
    __shared__ float part[5][HDIM];            // 4 KB

    {   // stage pre slab, summing k-split partials (coalesced)
        const float4* ps = (const float4*)(pre + (size_t)b * 64 * HDIM);
        float4* pd = (float4*)preS;
        const size_t pq = (size_t)pstride / 4;      // float4 stride
        for (int i = tid; i < 3200; i += 512) {
            float4 s = ps[i];
            for (int r = 1; r < nparts; ++r) {
                float4 v = ps[(size_t)r * pq + i];
                s.x += v.x; s.y += v.y; s.z += v.z; s.w += v.w;
            }
            pd[i] = s;
        }
    }

    const bool act = tid < 500;
    const int g  = tid / 5;             // n-group 0..99 (act threads)
    const int s5 = tid - g * 5;         // k-slice 0..4
    const int n0 = g * 2;
    const int k0 = s5 * 40;
    // clamped indices so tail threads (500..511) load valid addresses
    const int gl  = g > 99 ? 99 : g;
    const int s5l = g > 99 ? 4  : s5;

    // w in 20 float4 VGPR quads, loaded unconditionally, remat-pinned.
    const float* wr0 = Whh + (size_t)(gl * 2) * HDIM + s5l * 40;
    const float* wr1 = wr0 + HDIM;
    float4 w0_0 = *(const float4*)(wr0 +  0), w0_1 = *(const float4*)(wr0 +  4);
    float4 w0_2 = *(const float4*)(wr0 +  8), w0_3 = *(const float4*)(wr0 + 12);
    float4 w0_4 = *(const float4*)(wr0 + 16), w0_5 = *(const float4*)(wr0 + 20);
    float4 w0_6 = *(const float4*)(wr0 + 24), w0_7 = *(const float4*)(wr0 + 28);
    float4 w0_8 = *(const float4*)(wr0 + 32), w0_9 = *(const float4*)(wr0 + 36);
    float4 w1_0 = *(const float4*)(wr1 +  0), w1_1 = *(const float4*)(wr1 +  4);
    float4 w1_2 = *(const float4*)(wr1 +  8), w1_3 = *(const float4*)(wr1 + 12);
    float4 w1_4 = *(const float4*)(wr1 + 16), w1_5 = *(const float4*)(wr1 + 20);
    float4 w1_6 = *(const float4*)(wr1 + 24), w1_7 = *(const float4*)(wr1 + 28);
    float4 w1_8 = *(const float4*)(wr1 + 32), w1_9 = *(const float4*)(wr1 + 36);
    PIN4(w0_0); PIN4(w0_1); PIN4(w0_2); PIN4(w0_3); PIN4(w0_4);
    PIN4(w0_5); PIN4(w0_6); PIN4(w0_7); PIN4(w0_8); PIN4(w0_9);
    PIN4(w1_0); PIN4(w1_1); PIN4(w1_2); PIN4(w1_3); PIN4(w1_4);
    PIN4(w1_5); PIN4(w1_6); PIN4(w1_7); PIN4(w1_8); PIN4(w1_9);

    if (tid < HDIM) { bias[tid] = bih[tid] + bhh[tid]; h[tid] = 0.f; }
    __syncthreads();

#define DOT4(wv, hv) ((wv).x*(hv).x + (wv).y*(hv).y + (wv).z*(hv).z + (wv).w*(hv).w)

    for (int t = 0; t < 64; ++t) {
        if (act) {
            const float4 hv0 = *(const float4*)&h[k0 +  0];
            const float4 hv1 = *(const float4*)&h[k0 +  4];
            const float4 hv2 = *(const float4*)&h[k0 +  8];
            const float4 hv3 = *(const float4*)&h[k0 + 12];
            const float4 hv4 = *(const float4*)&h[k0 + 16];
            const float4 hv5 = *(const float4*)&h[k0 + 20];
            const float4 hv6 = *(const float4*)&h[k0 + 24];
            const float4 hv7 = *(const float4*)&h[k0 + 28];
            const float4 hv8 = *(const float4*)&h[k0 + 32];
            const float4 hv9 = *(const float4*)&h[k0 + 36];
            float a0 = (DOT4(w0_0,hv0)+DOT4(w0_1,hv1)+DOT4(w0_2,hv2)+DOT4(w0_3,hv3)+DOT4(w0_4,hv4))
                     + (DOT4(w0_5,hv5)+DOT4(w0_6,hv6)+DOT4(w0_7,hv7)+DOT4(w0_8,hv8)+DOT4(w0_9,hv9));
            float a1 = (DOT4(w1_0,hv0)+DOT4(w1_1,hv1)+DOT4(w1_2,hv2)+DOT4(w1_3,hv3)+DOT4(w1_4,hv4))
                     + (DOT4(w1_5,hv5)+DOT4(w1_6,hv6)+DOT4(w1_7,hv7)+DOT4(w1_8,hv8)+DOT4(w1_9,hv9));
            *(float2*)&part[s5][n0] = make_float2(a0, a1);
        }
        __syncthreads();   // part ready; h no longer read this step (LDS only)
        if (tid < HDIM) {
            float sum = part[0][tid] + part[1][tid] + part[2][tid]
                      + part[3][tid] + part[4][tid];
            float v = fast_tanh(sum + preS[t * HDIM + tid] + bias[tid]);
            h[tid] = v;
            preS[t * HDIM + tid] = v;   // same-thread slot reuse: race-free
        }
        __syncthreads();   // h ready for step t+1; part free (LDS only)
    }

    {   // bulk store h slab -> Hout (coalesced float4)
        const float4* ps = (const float4*)preS;
        float4* pd = (float4*)(Hout + (size_t)b * 64 * HDIM);
        for (int i = tid; i < 3200; i += 512) pd[i] = ps[i];
    }

    // fused FC head (last layer only): h == h_63 in LDS
    if (fcw != nullptr && tid < 16) {
        const int cls = tid & 1, sl = tid >> 1;      // 8 slices of 25
        const float* fw = fcw + cls * HDIM + sl * 25;
        const float* hp = h + sl * 25;
        float sacc = 0.f;
#pragma unroll
        for (int j = 0; j < 25; ++j) sacc += hp[j] * fw[j];
        sacc += __shfl_xor(sacc, 2);
        sacc += __shfl_xor(sacc, 4);
        sacc += __shfl_xor(sacc, 8);
        if (sl == 0) outp[b * 2 + cls] = sacc + fcb[cls];
    }
}

extern "C" void kernel_launch(void* const* d_in, const int* in_sizes, int n_in,
                              void* d_out, int out_size, void* d_ws, size_t ws_size,
                              hipStream_t stream) {
    const float* x     = (const float*)d_in[0];
    const float* W_ih0 = (const float*)d_in[1];
    const float* W_hh0 = (const float*)d_in[2];
    const float* b_ih0 = (const float*)d_in[3];
    const float* b_hh0 = (const float*)d_in[4];
    const float* W_ih1 = (const float*)d_in[5];
    const float* W_hh1 = (const float*)d_in[6];
    const float* b_ih1 = (const float*)d_in[7];
    const float* b_hh1 = (const float*)d_in[8];
    const float* W_ih2 = (const float*)d_in[9];
    const float* W_hh2 = (const float*)d_in[10];
    const float* b_ih2 = (const float*)d_in[11];
    const float* b_hh2 = (const float*)d_in[12];
    const float* fc_w  = (const float*)d_in[13];
    const float* fc_b  = (const float*)d_in[14];
    float* out = (float*)d_out;

    const size_t PE = (size_t)2048 * HDIM;          // 409600
    float* P     = (float*)d_ws;
    float* Hbuf  = P + PE;
    float* Hbuf2 = Hbuf + PE;
    float* Ppart = Hbuf2 + PE;                      // 16 x 409600
    __bf16* W0p  = (__bf16*)(Ppart + 16 * PE);      // 320 chunks x 13312 bf16
    __bf16* W1p  = W0p + (size_t)320 * 13312;       // 7 chunks
    __bf16* W2p  = W1p + (size_t)7 * 13312;
    // total ws: ~40.0 MB

    // ---- prologue: pack all weights (one launch) ----
    pack_all<<<1024, 256, 0, stream>>>(W_ih0, W_ih1, W_ih2, W0p, W1p, W2p);

    // ---- layer 0: K=10000, 16-way k-split (20 ksteps each); partials are
    //      reduced inside rnn_rec's staging ----
    gemm_pipe<<<dim3(32, 16), 512, 0, stream>>>(x, 10000, 10000, W0p, Ppart, (int)PE, 20);
    rnn_rec<<<32, 512, 0, stream>>>(Ppart, 16, (int)PE, W_hh0, b_ih0, b_hh0,
                                    Hbuf, nullptr, nullptr, nullptr);

    // ---- layer 1: K=200, single split, direct store ----
    gemm_pipe<<<dim3(32, 1), 512, 0, stream>>>(Hbuf, HDIM, HDIM, W1p, P, (int)PE, 7);
    rnn_rec<<<32, 512, 0, stream>>>(P, 1, (int)PE, W_hh1, b_ih1, b_hh1,
                                    Hbuf2, nullptr, nullptr, nullptr);

    // ---- layer 2 + fused FC head ----
    gemm_pipe<<<dim3(32, 1), 512, 0, stream>>>(Hbuf2, HDIM, HDIM, W2p, P, (int)PE, 7);
    rnn_rec<<<32, 512, 0, stream>>>(P, 1, (int)PE, W_hh2, b_ih2, b_hh2,
                                    Hbuf, fc_w, fc_b, out);
}

// Round 5
// 329.859 us; speedup vs baseline: 1.0194x; 1.0148x over previous
//
#include <hip/hip_runtime.h>
#include <hip/hip_bf16.h>

// 3-layer tanh RNN. B=32, T=64, D_IN=10000, H=200, N_CLASSES=2.
//
// R12:
//  * rec: REVERT to R7's proven inner structure VERBATIM (w[80] flat array,
//    10-way k-split, 4 outputs/thread, part[10], 2 barriers, in-loop Hout
//    store). Evidence: R0's top-5 were all gemm@53us => R7 rec < 52us; every
//    restructured variant since (R8 shfl / R9 2x40 / R10 named / R11 pinned)
//    ran exactly 66.4us with VGPR 52-56 (weights evicted to scratch,
//    ~160KB/step reload at L2 BW ~= 2500cy/step). The eviction trigger is
//    shape-sensitive codegen; stop fighting it, use the shape that works.
//    Additions kept OUTSIDE the step loop: nparts partial-sum staging
//    prologue (R8 ran 66 without it -> exonerated), fused FC head.
//  * launch structure from R9 (7 launches); gemm from R8 (BM=64, 2
//    blocks/CU) unchanged.
//  * split-bf16 3-term everywhere: ~fp32 accuracy at bf16 MFMA rate.

typedef __bf16  bf16x8 __attribute__((ext_vector_type(8)));
typedef __bf16  bf16x4 __attribute__((ext_vector_type(4)));
typedef float   f32x4  __attribute__((ext_vector_type(4)));

#define HDIM 200
#define BM 64
#define CHUNK_B 26624   // bytes per packed k-chunk: [208x32] hi (13312) + lo
#define MFMA(a, b, c) __builtin_amdgcn_mfma_f32_16x16x32_bf16(a, b, c, 0, 0, 0)

__device__ __forceinline__ void glds16(const void* g, void* l) {
    __builtin_amdgcn_global_load_lds(
        (const __attribute__((address_space(1))) unsigned int*)g,
        (__attribute__((address_space(3))) unsigned int*)l, 16, 0, 0);
}

// ---- pack W [HDIM x K] fp32 -> chunks: [kc][208 rows x 32 k] bf16 hi, lo ----
// One launch packs all three W_ih weights (W0 dominates: 320 of 334 chunks).
__global__ void pack_all(const float* __restrict__ W0,
                         const float* __restrict__ W1,
                         const float* __restrict__ W2,
                         __bf16* __restrict__ O0,
                         __bf16* __restrict__ O1,
                         __bf16* __restrict__ O2)
{
    const int T0 = 320 * 1664, T1 = 7 * 1664, T2 = 7 * 1664;
    for (int gt = blockIdx.x * blockDim.x + threadIdx.x; gt < T0 + T1 + T2;
         gt += gridDim.x * blockDim.x) {
        const float* W; __bf16* out; int K, g;
        if (gt < T0)           { W = W0; out = O0; K = 10000; g = gt; }
        else if (gt < T0 + T1) { W = W1; out = O1; K = HDIM;  g = gt - T0; }
        else                   { W = W2; out = O2; K = HDIM;  g = gt - T0 - T1; }

        const int kc = g / 1664;
        const int o  = g - kc * 1664;
        const int isLo = (o >= 832);
        const int o2 = isLo ? o - 832 : o;
        const int r  = o2 >> 2;              // 0..207
        const int k  = kc * 32 + (o2 & 3) * 8;
        bf16x8 v;
        if (r < HDIM && k < K) {             // K % 8 == 0
            const float* p = W + (size_t)r * K + k;
            float4 a = *(const float4*)p, b = *(const float4*)(p + 4);
            float f[8] = {a.x, a.y, a.z, a.w, b.x, b.y, b.z, b.w};
#pragma unroll
            for (int i = 0; i < 8; ++i) {
                __bf16 h = (__bf16)f[i];
                v[i] = isLo ? (__bf16)(f[i] - (float)h) : h;
            }
        } else {
#pragma unroll
            for (int i = 0; i < 8; ++i) v[i] = (__bf16)0.f;
        }
        *(bf16x8*)&out[(size_t)g * 8] = v;
    }
}

// ---- pipelined GEMM: C[m][n] = sum_k A[m][k]*W[n][k] over this block's k ----
// BM=64 (4 Mtiles). 8 waves = 2 M-groups (2 Mtiles each) x 4 N-groups
// (4/3/3/3 ntiles). One barrier/kstep. 68 KB LDS -> 2 blocks/CU.
__global__ __launch_bounds__(512, 4)
void gemm_pipe(const float* __restrict__ A, int lda, int K,
               const __bf16* __restrict__ Bpack,
               float* __restrict__ Cbase, int per_split, int ksteps)
{
    __shared__ alignas(16) __bf16 Ab[2][4096];    // [hi 2048 | lo 2048] (64x32)
    __shared__ alignas(16) __bf16 Bb[2][13312];   // [hi 6656 | lo 6656] (208x32)

    const int tid = threadIdx.x;
    const int kc0 = blockIdx.y * ksteps;
    const int m0  = blockIdx.x * BM;
    float* __restrict__ C = Cbase + (size_t)blockIdx.y * per_split;

    const int wv = tid >> 6, lane = tid & 63;
    const int r16 = lane & 15, kg = lane >> 4;
    const int mg = wv & 1, ng = wv >> 1;
    const int nt0 = ng ? 1 + ng * 3 : 0;        // 0,4,7,10
    const int ntw = ng ? 3 : 4;

    const int a_row = tid >> 3;          // 0..63
    const int a_q   = tid & 7;           // float4 column group
    const float* Arow = A + (size_t)(m0 + a_row) * lda + a_q * 4;

    f32x4 acc[2][4];
#pragma unroll
    for (int mi = 0; mi < 2; ++mi)
#pragma unroll
        for (int j = 0; j < 4; ++j) acc[mi][j] = (f32x4)0.f;

    float av[4];
    auto loadA = [&](int ks) {
        const int kb = (kc0 + ks) * 32;
        if (kb + a_q * 4 < K) {          // 4-granular, K % 4 == 0
            float4 x0 = *(const float4*)(Arow + kb);
            av[0] = x0.x; av[1] = x0.y; av[2] = x0.z; av[3] = x0.w;
        } else {
#pragma unroll
            for (int i = 0; i < 4; ++i) av[i] = 0.f;
        }
    };
    auto issueB = [&](int ks, int buf) {
        const char* src = (const char*)Bpack + (size_t)(kc0 + ks) * CHUNK_B;
        char* dst = (char*)&Bb[buf][0];
#pragma unroll
        for (int r = 0; r < 3; ++r)
            glds16(src + (r * 512 + tid) * 16, dst + (r * 512 + tid) * 16);
        if (tid < 128)
            glds16(src + (1536 + tid) * 16, dst + (1536 + tid) * 16);
    };

    loadA(0);
    issueB(0, 0);

    for (int ks = 0; ks < ksteps; ++ks) {
        const int cur = ks & 1, nxt = cur ^ 1;
        // commit A regs -> LDS hi/lo  (Ab[cur] last read in iter ks-2: safe)
        bf16x4 th, tl;
#pragma unroll
        for (int i = 0; i < 4; ++i) {
            __bf16 h = (__bf16)av[i];
            th[i] = h; tl[i] = (__bf16)(av[i] - (float)h);
        }
        *(bf16x4*)&Ab[cur][a_row * 32 + a_q * 4]        = th;
        *(bf16x4*)&Ab[cur][2048 + a_row * 32 + a_q * 4] = tl;
        __syncthreads();   // drains glds B(ks)->Bb[cur] + A writes (vmcnt+lgkm)
        if (ks + 1 < ksteps) { issueB(ks + 1, nxt); loadA(ks + 1); }

        const int ao0 = (mg * 32 + r16) * 32 + kg * 8;
        const int ao1 = ao0 + 16 * 32;
        bf16x8 ah0 = *(const bf16x8*)&Ab[cur][ao0];
        bf16x8 al0 = *(const bf16x8*)&Ab[cur][2048 + ao0];
        bf16x8 ah1 = *(const bf16x8*)&Ab[cur][ao1];
        bf16x8 al1 = *(const bf16x8*)&Ab[cur][2048 + ao1];
#pragma unroll
        for (int j = 0; j < 4; ++j) {
            if (j < ntw) {
                const int bo = ((nt0 + j) * 16 + r16) * 32 + kg * 8;
                bf16x8 bh = *(const bf16x8*)&Bb[cur][bo];
                bf16x8 bl = *(const bf16x8*)&Bb[cur][6656 + bo];
                acc[0][j] = MFMA(al0, bh, acc[0][j]);
                acc[0][j] = MFMA(ah0, bl, acc[0][j]);
                acc[0][j] = MFMA(ah0, bh, acc[0][j]);
                acc[1][j] = MFMA(al1, bh, acc[1][j]);
                acc[1][j] = MFMA(ah1, bl, acc[1][j]);
                acc[1][j] = MFMA(ah1, bh, acc[1][j]);
            }
        }
    }

    // epilogue: C/D layout col=lane&15, row=(lane>>4)*4+reg; plain stores
#pragma unroll
    for (int mi = 0; mi < 2; ++mi) {
        const int rb = m0 + mg * 32 + mi * 16 + kg * 4;
#pragma unroll
        for (int j = 0; j < 4; ++j) {
            if (j < ntw) {
                const int n = (nt0 + j) * 16 + r16;
                if (n < HDIM)
#pragma unroll
                    for (int r = 0; r < 4; ++r)
                        C[(size_t)(rb + r) * HDIM + n] = acc[mi][j][r];
            }
        }
    }
}

__device__ __forceinline__ float fast_tanh(float x) {
    float e = __expf(-2.f * fabsf(x));
    float r = (1.f - e) / (1.f + e);
    return copysignf(r, x);
}

// ---- recurrence: R7-verbatim inner structure. 1 block/batch; thread owns
// 4 n x 20 k; w[80] in VGPRs (R7-proven no-spill shape); 10-way k-split,
// part[10] LDS reduce, 2 barriers/step, in-loop Hout store.
// Outside the loop: nparts partial-sum staging prologue + fused FC head. ----
__global__ __launch_bounds__(512, 1)
void rnn_rec(const float* __restrict__ pre,   // [nparts][32][64][200] partials
             int nparts, int pstride,          // floats between partials
             const float* __restrict__ Whh,   // [200][200]
             const float* __restrict__ bih,
             const float* __restrict__ bhh,
             float* __restrict__ Hout,        // [32][64][200]
             const float* __restrict__ fcw,   // [2][200] or nullptr
             const float* __restrict__ fcb,
             float* __restrict__ outp)        // [32][2]
{
    const int b   = blockIdx.x;
    const int tid = threadIdx.x;

    __shared__ float preS[64 * HDIM];          // 51.2 KB
    __shared__ float h[HDIM];
    __shared__ float bias[HDIM];
    __shared__ float part[10][HDIM];           // 8 KB

    {   // stage pre slab, summing k-split partials (coalesced)
        const float4* ps = (const float4*)(pre + (size_t)b * 64 * HDIM);
        float4* pd = (float4*)preS;
        const size_t pq = (size_t)pstride / 4;      // float4 stride
        for (int i = tid; i < 3200; i += 512) {
            float4 s = ps[i];
            for (int r = 1; r < nparts; ++r) {
                float4 v = ps[(size_t)r * pq + i];
                s.x += v.x; s.y += v.y; s.z += v.z; s.w += v.w;
            }
            pd[i] = s;
        }
    }

    const bool act = tid < 500;
    const int g  = tid / 10;            // n-group 0..49
    const int s  = tid - g * 10;        // k-slice 0..9
    const int n0 = g * 4;
    const int k0 = s * 20;

    float w[80];
    if (act) {
#pragma unroll
        for (int j = 0; j < 4; ++j) {
            const float* wr = Whh + (size_t)(n0 + j) * HDIM + k0;
#pragma unroll
            for (int i = 0; i < 5; ++i) {
                float4 v = *(const float4*)(wr + i * 4);
                w[j * 20 + i * 4 + 0] = v.x; w[j * 20 + i * 4 + 1] = v.y;
                w[j * 20 + i * 4 + 2] = v.z; w[j * 20 + i * 4 + 3] = v.w;
            }
        }
    }
    if (tid < HDIM) { bias[tid] = bih[tid] + bhh[tid]; h[tid] = 0.f; }
    __syncthreads();

    for (int t = 0; t < 64; ++t) {
        if (act) {
            float a0 = 0.f, a1 = 0.f, a2 = 0.f, a3 = 0.f;
#pragma unroll
            for (int i = 0; i < 5; ++i) {
                float4 hv = *(const float4*)&h[k0 + i * 4];
                a0 += w[ 0 + i*4]*hv.x + w[ 1 + i*4]*hv.y + w[ 2 + i*4]*hv.z + w[ 3 + i*4]*hv.w;
                a1 += w[20 + i*4]*hv.x + w[21 + i*4]*hv.y + w[22 + i*4]*hv.z + w[23 + i*4]*hv.w;
                a2 += w[40 + i*4]*hv.x + w[41 + i*4]*hv.y + w[42 + i*4]*hv.z + w[43 + i*4]*hv.w;
                a3 += w[60 + i*4]*hv.x + w[61 + i*4]*hv.y + w[62 + i*4]*hv.z + w[63 + i*4]*hv.w;
            }
            float4 pv = make_float4(a0, a1, a2, a3);
            *(float4*)&part[s][n0] = pv;
        }
        __syncthreads();
        if (tid < HDIM) {
            float sum = part[0][tid];
#pragma unroll
            for (int r = 1; r < 10; ++r) sum += part[r][tid];
            float v = fast_tanh(sum + preS[t * HDIM + tid] + bias[tid]);
            h[tid] = v;
            Hout[((size_t)b * 64 + t) * HDIM + tid] = v;
        }
        __syncthreads();
    }

    // fused FC head (last layer only): h == h_63 in LDS
    if (fcw != nullptr && tid < 16) {
        const int cls = tid & 1, sl = tid >> 1;      // 8 slices of 25
        const float* fw = fcw + cls * HDIM + sl * 25;
        const float* hp = h + sl * 25;
        float sacc = 0.f;
#pragma unroll
        for (int j = 0; j < 25; ++j) sacc += hp[j] * fw[j];
        sacc += __shfl_xor(sacc, 2);
        sacc += __shfl_xor(sacc, 4);
        sacc += __shfl_xor(sacc, 8);
        if (sl == 0) outp[b * 2 + cls] = sacc + fcb[cls];
    }
}

extern "C" void kernel_launch(void* const* d_in, const int* in_sizes, int n_in,
                              void* d_out, int out_size, void* d_ws, size_t ws_size,
                              hipStream_t stream) {
    const float* x     = (const float*)d_in[0];
    const float* W_ih0 = (const float*)d_in[1];
    const float* W_hh0 = (const float*)d_in[2];
    const float* b_ih0 = (const float*)d_in[3];
    const float* b_hh0 = (const float*)d_in[4];
    const float* W_ih1 = (const float*)d_in[5];
    const float* W_hh1 = (const float*)d_in[6];
    const float* b_ih1 = (const float*)d_in[7];
    const float* b_hh1 = (const float*)d_in[8];
    const float* W_ih2 = (const float*)d_in[9];
    const float* W_hh2 = (const float*)d_in[10];
    const float* b_ih2 = (const float*)d_in[11];
    const float* b_hh2 = (const float*)d_in[12];
    const float* fc_w  = (const float*)d_in[13];
    const float* fc_b  = (const float*)d_in[14];
    float* out = (float*)d_out;

    const size_t PE = (size_t)2048 * HDIM;          // 409600
    float* P     = (float*)d_ws;
    float* Hbuf  = P + PE;
    float* Hbuf2 = Hbuf + PE;
    float* Ppart = Hbuf2 + PE;                      // 16 x 409600
    __bf16* W0p  = (__bf16*)(Ppart + 16 * PE);      // 320 chunks x 13312 bf16
    __bf16* W1p  = W0p + (size_t)320 * 13312;       // 7 chunks
    __bf16* W2p  = W1p + (size_t)7 * 13312;
    // total ws: ~40.0 MB

    // ---- prologue: pack all weights (one launch) ----
    pack_all<<<1024, 256, 0, stream>>>(W_ih0, W_ih1, W_ih2, W0p, W1p, W2p);

    // ---- layer 0: K=10000, 16-way k-split (20 ksteps each); partials are
    //      reduced inside rnn_rec's staging ----
    gemm_pipe<<<dim3(32, 16), 512, 0, stream>>>(x, 10000, 10000, W0p, Ppart, (int)PE, 20);
    rnn_rec<<<32, 512, 0, stream>>>(Ppart, 16, (int)PE, W_hh0, b_ih0, b_hh0,
                                    Hbuf, nullptr, nullptr, nullptr);

    // ---- layer 1: K=200, single split, direct store ----
    gemm_pipe<<<dim3(32, 1), 512, 0, stream>>>(Hbuf, HDIM, HDIM, W1p, P, (int)PE, 7);
    rnn_rec<<<32, 512, 0, stream>>>(P, 1, (int)PE, W_hh1, b_ih1, b_hh1,
                                    Hbuf2, nullptr, nullptr, nullptr);

    // ---- layer 2 + fused FC head ----
    gemm_pipe<<<dim3(32, 1), 512, 0, stream>>>(Hbuf2, HDIM, HDIM, W2p, P, (int)PE, 7);
    rnn_rec<<<32, 512, 0, stream>>>(P, 1, (int)PE, W_hh2, b_ih2, b_hh2,
                                    Hbuf, fc_w, fc_b, out);
}

// Round 6
// 314.884 us; speedup vs baseline: 1.0679x; 1.0476x over previous
//
#include <hip/hip_runtime.h>
#include <hip/hip_bf16.h>

// 3-layer tanh RNN. B=32, T=64, D_IN=10000, H=200, N_CLASSES=2.
//
// R13:
//  * rec: BYTE-EXACT R7 restoration of the whole KERNEL (signature, staging,
//    body, no FC head). R12 restored only the inner loop and still spilled
//    (VGPR=60, 64us): regalloc is a whole-function decision, and the added
//    nparts-prologue/fc-head flipped it. Separate reduce_parts + fc_head
//    kernels reinstated (R7-verbatim). The ~36us/iter rec penalty was not
//    worth the ~10us of launch savings.
//  * gemm: R8 BM=64 / 2-blocks-per-CU version kept (occupancy fix).
//  * pack_all single launch kept (separate kernel; low codegen-perturbation
//    risk -- revert to 3x pack_w next if rec is still slow).
//  * split-bf16 3-term everywhere: ~fp32 accuracy at bf16 MFMA rate.

typedef __bf16  bf16x8 __attribute__((ext_vector_type(8)));
typedef __bf16  bf16x4 __attribute__((ext_vector_type(4)));
typedef float   f32x4  __attribute__((ext_vector_type(4)));

#define HDIM 200
#define BM 64
#define CHUNK_B 26624   // bytes per packed k-chunk: [208x32] hi (13312) + lo
#define MFMA(a, b, c) __builtin_amdgcn_mfma_f32_16x16x32_bf16(a, b, c, 0, 0, 0)

__device__ __forceinline__ void glds16(const void* g, void* l) {
    __builtin_amdgcn_global_load_lds(
        (const __attribute__((address_space(1))) unsigned int*)g,
        (__attribute__((address_space(3))) unsigned int*)l, 16, 0, 0);
}

// ---- pack W [HDIM x K] fp32 -> chunks: [kc][208 rows x 32 k] bf16 hi, lo ----
// One launch packs all three W_ih weights (W0 dominates: 320 of 334 chunks).
__global__ void pack_all(const float* __restrict__ W0,
                         const float* __restrict__ W1,
                         const float* __restrict__ W2,
                         __bf16* __restrict__ O0,
                         __bf16* __restrict__ O1,
                         __bf16* __restrict__ O2)
{
    const int T0 = 320 * 1664, T1 = 7 * 1664, T2 = 7 * 1664;
    for (int gt = blockIdx.x * blockDim.x + threadIdx.x; gt < T0 + T1 + T2;
         gt += gridDim.x * blockDim.x) {
        const float* W; __bf16* out; int K, g;
        if (gt < T0)           { W = W0; out = O0; K = 10000; g = gt; }
        else if (gt < T0 + T1) { W = W1; out = O1; K = HDIM;  g = gt - T0; }
        else                   { W = W2; out = O2; K = HDIM;  g = gt - T0 - T1; }

        const int kc = g / 1664;
        const int o  = g - kc * 1664;
        const int isLo = (o >= 832);
        const int o2 = isLo ? o - 832 : o;
        const int r  = o2 >> 2;              // 0..207
        const int k  = kc * 32 + (o2 & 3) * 8;
        bf16x8 v;
        if (r < HDIM && k < K) {             // K % 8 == 0
            const float* p = W + (size_t)r * K + k;
            float4 a = *(const float4*)p, b = *(const float4*)(p + 4);
            float f[8] = {a.x, a.y, a.z, a.w, b.x, b.y, b.z, b.w};
#pragma unroll
            for (int i = 0; i < 8; ++i) {
                __bf16 h = (__bf16)f[i];
                v[i] = isLo ? (__bf16)(f[i] - (float)h) : h;
            }
        } else {
#pragma unroll
            for (int i = 0; i < 8; ++i) v[i] = (__bf16)0.f;
        }
        *(bf16x8*)&out[(size_t)g * 8] = v;
    }
}

// ---- pipelined GEMM: C[m][n] = sum_k A[m][k]*W[n][k] over this block's k ----
// BM=64 (4 Mtiles). 8 waves = 2 M-groups (2 Mtiles each) x 4 N-groups
// (4/3/3/3 ntiles). One barrier/kstep. 68 KB LDS -> 2 blocks/CU.
__global__ __launch_bounds__(512, 4)
void gemm_pipe(const float* __restrict__ A, int lda, int K,
               const __bf16* __restrict__ Bpack,
               float* __restrict__ Cbase, int per_split, int ksteps)
{
    __shared__ alignas(16) __bf16 Ab[2][4096];    // [hi 2048 | lo 2048] (64x32)
    __shared__ alignas(16) __bf16 Bb[2][13312];   // [hi 6656 | lo 6656] (208x32)

    const int tid = threadIdx.x;
    const int kc0 = blockIdx.y * ksteps;
    const int m0  = blockIdx.x * BM;
    float* __restrict__ C = Cbase + (size_t)blockIdx.y * per_split;

    const int wv = tid >> 6, lane = tid & 63;
    const int r16 = lane & 15, kg = lane >> 4;
    const int mg = wv & 1, ng = wv >> 1;
    const int nt0 = ng ? 1 + ng * 3 : 0;        // 0,4,7,10
    const int ntw = ng ? 3 : 4;

    const int a_row = tid >> 3;          // 0..63
    const int a_q   = tid & 7;           // float4 column group
    const float* Arow = A + (size_t)(m0 + a_row) * lda + a_q * 4;

    f32x4 acc[2][4];
#pragma unroll
    for (int mi = 0; mi < 2; ++mi)
#pragma unroll
        for (int j = 0; j < 4; ++j) acc[mi][j] = (f32x4)0.f;

    float av[4];
    auto loadA = [&](int ks) {
        const int kb = (kc0 + ks) * 32;
        if (kb + a_q * 4 < K) {          // 4-granular, K % 4 == 0
            float4 x0 = *(const float4*)(Arow + kb);
            av[0] = x0.x; av[1] = x0.y; av[2] = x0.z; av[3] = x0.w;
        } else {
#pragma unroll
            for (int i = 0; i < 4; ++i) av[i] = 0.f;
        }
    };
    auto issueB = [&](int ks, int buf) {
        const char* src = (const char*)Bpack + (size_t)(kc0 + ks) * CHUNK_B;
        char* dst = (char*)&Bb[buf][0];
#pragma unroll
        for (int r = 0; r < 3; ++r)
            glds16(src + (r * 512 + tid) * 16, dst + (r * 512 + tid) * 16);
        if (tid < 128)
            glds16(src + (1536 + tid) * 16, dst + (1536 + tid) * 16);
    };

    loadA(0);
    issueB(0, 0);

    for (int ks = 0; ks < ksteps; ++ks) {
        const int cur = ks & 1, nxt = cur ^ 1;
        // commit A regs -> LDS hi/lo  (Ab[cur] last read in iter ks-2: safe)
        bf16x4 th, tl;
#pragma unroll
        for (int i = 0; i < 4; ++i) {
            __bf16 h = (__bf16)av[i];
            th[i] = h; tl[i] = (__bf16)(av[i] - (float)h);
        }
        *(bf16x4*)&Ab[cur][a_row * 32 + a_q * 4]        = th;
        *(bf16x4*)&Ab[cur][2048 + a_row * 32 + a_q * 4] = tl;
        __syncthreads();   // drains glds B(ks)->Bb[cur] + A writes (vmcnt+lgkm)
        if (ks + 1 < ksteps) { issueB(ks + 1, nxt); loadA(ks + 1); }

        const int ao0 = (mg * 32 + r16) * 32 + kg * 8;
        const int ao1 = ao0 + 16 * 32;
        bf16x8 ah0 = *(const bf16x8*)&Ab[cur][ao0];
        bf16x8 al0 = *(const bf16x8*)&Ab[cur][2048 + ao0];
        bf16x8 ah1 = *(const bf16x8*)&Ab[cur][ao1];
        bf16x8 al1 = *(const bf16x8*)&Ab[cur][2048 + ao1];
#pragma unroll
        for (int j = 0; j < 4; ++j) {
            if (j < ntw) {
                const int bo = ((nt0 + j) * 16 + r16) * 32 + kg * 8;
                bf16x8 bh = *(const bf16x8*)&Bb[cur][bo];
                bf16x8 bl = *(const bf16x8*)&Bb[cur][6656 + bo];
                acc[0][j] = MFMA(al0, bh, acc[0][j]);
                acc[0][j] = MFMA(ah0, bl, acc[0][j]);
                acc[0][j] = MFMA(ah0, bh, acc[0][j]);
                acc[1][j] = MFMA(al1, bh, acc[1][j]);
                acc[1][j] = MFMA(ah1, bl, acc[1][j]);
                acc[1][j] = MFMA(ah1, bh, acc[1][j]);
            }
        }
    }

    // epilogue: C/D layout col=lane&15, row=(lane>>4)*4+reg; plain stores
#pragma unroll
    for (int mi = 0; mi < 2; ++mi) {
        const int rb = m0 + mg * 32 + mi * 16 + kg * 4;
#pragma unroll
        for (int j = 0; j < 4; ++j) {
            if (j < ntw) {
                const int n = (nt0 + j) * 16 + r16;
                if (n < HDIM)
#pragma unroll
                    for (int r = 0; r < 4; ++r)
                        C[(size_t)(rb + r) * HDIM + n] = acc[mi][j][r];
            }
        }
    }
}

// ---- sum 16 k-split partials ----
__global__ void reduce_parts(const float* __restrict__ Pp, float* __restrict__ P)
{
    const int i = blockIdx.x * blockDim.x + threadIdx.x;   // float4 index
    if (i < 102400) {
        float4 s = ((const float4*)Pp)[i];
#pragma unroll
        for (int r = 1; r < 16; ++r) {
            float4 v = ((const float4*)Pp)[(size_t)r * 102400 + i];
            s.x += v.x; s.y += v.y; s.z += v.z; s.w += v.w;
        }
        ((float4*)P)[i] = s;
    }
}

__device__ __forceinline__ float fast_tanh(float x) {
    float e = __expf(-2.f * fabsf(x));
    float r = (1.f - e) / (1.f + e);
    return copysignf(r, x);
}

// ---- recurrence: 1 block/batch; thread owns 4 n x 20 k; w[80] in VGPRs ----
// BYTE-EXACT R7 kernel (do not add anything to this function).
__global__ __launch_bounds__(512, 1)
void rnn_rec(const float* __restrict__ pre,   // [32][64][200] (GEMM only)
             const float* __restrict__ Whh,   // [200][200]
             const float* __restrict__ bih,
             const float* __restrict__ bhh,
             float* __restrict__ Hout)        // [32][64][200]
{
    const int b   = blockIdx.x;
    const int tid = threadIdx.x;

    __shared__ float preS[64 * HDIM];          // 51.2 KB
    __shared__ float h[HDIM];
    __shared__ float bias[HDIM];
    __shared__ float part[10][HDIM];           // 8 KB

    {   // stage pre slab (coalesced)
        const float4* ps = (const float4*)(pre + (size_t)b * 64 * HDIM);
        float4* pd = (float4*)preS;
        for (int i = tid; i < 3200; i += 512) pd[i] = ps[i];
    }

    const bool act = tid < 500;
    const int g  = tid / 10;            // n-group 0..49
    const int s  = tid - g * 10;        // k-slice 0..9
    const int n0 = g * 4;
    const int k0 = s * 20;

    float w[80];
    if (act) {
#pragma unroll
        for (int j = 0; j < 4; ++j) {
            const float* wr = Whh + (size_t)(n0 + j) * HDIM + k0;
#pragma unroll
            for (int i = 0; i < 5; ++i) {
                float4 v = *(const float4*)(wr + i * 4);
                w[j * 20 + i * 4 + 0] = v.x; w[j * 20 + i * 4 + 1] = v.y;
                w[j * 20 + i * 4 + 2] = v.z; w[j * 20 + i * 4 + 3] = v.w;
            }
        }
    }
    if (tid < HDIM) { bias[tid] = bih[tid] + bhh[tid]; h[tid] = 0.f; }
    __syncthreads();

    for (int t = 0; t < 64; ++t) {
        if (act) {
            float a0 = 0.f, a1 = 0.f, a2 = 0.f, a3 = 0.f;
#pragma unroll
            for (int i = 0; i < 5; ++i) {
                float4 hv = *(const float4*)&h[k0 + i * 4];
                a0 += w[ 0 + i*4]*hv.x + w[ 1 + i*4]*hv.y + w[ 2 + i*4]*hv.z + w[ 3 + i*4]*hv.w;
                a1 += w[20 + i*4]*hv.x + w[21 + i*4]*hv.y + w[22 + i*4]*hv.z + w[23 + i*4]*hv.w;
                a2 += w[40 + i*4]*hv.x + w[41 + i*4]*hv.y + w[42 + i*4]*hv.z + w[43 + i*4]*hv.w;
                a3 += w[60 + i*4]*hv.x + w[61 + i*4]*hv.y + w[62 + i*4]*hv.z + w[63 + i*4]*hv.w;
            }
            float4 pv = make_float4(a0, a1, a2, a3);
            *(float4*)&part[s][n0] = pv;
        }
        __syncthreads();
        if (tid < HDIM) {
            float sum = part[0][tid];
#pragma unroll
            for (int r = 1; r < 10; ++r) sum += part[r][tid];
            float v = fast_tanh(sum + preS[t * HDIM + tid] + bias[tid]);
            h[tid] = v;
            Hout[((size_t)b * 64 + t) * HDIM + tid] = v;
        }
        __syncthreads();
    }
}

// Wrong-index bug note: w[j*20 + i*4 + c] is written; the FMA block above
// indexes w[c + i*4] for j=0 etc. -- offsets 0/20/40/60 match j*20. OK.

// ---- trivially-correct FC head ----
__global__ void fc_head(const float* __restrict__ Hlast_base,
                        const float* __restrict__ fcw,
                        const float* __restrict__ fcb,
                        float* __restrict__ out)
{
    const int i = threadIdx.x;
    if (i >= 64) return;
    const int b = i >> 1, cls = i & 1;
    const float* hp = Hlast_base + ((size_t)b * 64 + 63) * HDIM;
    const float* fw = fcw + cls * HDIM;
    float s = fcb[cls];
    for (int j = 0; j < HDIM; ++j) s += hp[j] * fw[j];
    out[b * 2 + cls] = s;
}

extern "C" void kernel_launch(void* const* d_in, const int* in_sizes, int n_in,
                              void* d_out, int out_size, void* d_ws, size_t ws_size,
                              hipStream_t stream) {
    const float* x     = (const float*)d_in[0];
    const float* W_ih0 = (const float*)d_in[1];
    const float* W_hh0 = (const float*)d_in[2];
    const float* b_ih0 = (const float*)d_in[3];
    const float* b_hh0 = (const float*)d_in[4];
    const float* W_ih1 = (const float*)d_in[5];
    const float* W_hh1 = (const float*)d_in[6];
    const float* b_ih1 = (const float*)d_in[7];
    const float* b_hh1 = (const float*)d_in[8];
    const float* W_ih2 = (const float*)d_in[9];
    const float* W_hh2 = (const float*)d_in[10];
    const float* b_ih2 = (const float*)d_in[11];
    const float* b_hh2 = (const float*)d_in[12];
    const float* fc_w  = (const float*)d_in[13];
    const float* fc_b  = (const float*)d_in[14];
    float* out = (float*)d_out;

    const size_t PE = (size_t)2048 * HDIM;          // 409600
    float* P     = (float*)d_ws;
    float* Hbuf  = P + PE;
    float* Hbuf2 = Hbuf + PE;
    float* Ppart = Hbuf2 + PE;                      // 16 x 409600
    __bf16* W0p  = (__bf16*)(Ppart + 16 * PE);      // 320 chunks x 13312 bf16
    __bf16* W1p  = W0p + (size_t)320 * 13312;       // 7 chunks
    __bf16* W2p  = W1p + (size_t)7 * 13312;
    // total ws: ~40.0 MB

    // ---- prologue: pack all weights (one launch) ----
    pack_all<<<1024, 256, 0, stream>>>(W_ih0, W_ih1, W_ih2, W0p, W1p, W2p);

    // ---- layer 0: K=10000, 16-way k-split (20 ksteps each), partials ----
    gemm_pipe<<<dim3(32, 16), 512, 0, stream>>>(x, 10000, 10000, W0p, Ppart, (int)PE, 20);
    reduce_parts<<<400, 256, 0, stream>>>(Ppart, P);
    rnn_rec<<<32, 512, 0, stream>>>(P, W_hh0, b_ih0, b_hh0, Hbuf);

    // ---- layer 1: K=200, single split, direct store ----
    gemm_pipe<<<dim3(32, 1), 512, 0, stream>>>(Hbuf, HDIM, HDIM, W1p, P, (int)PE, 7);
    rnn_rec<<<32, 512, 0, stream>>>(P, W_hh1, b_ih1, b_hh1, Hbuf2);

    // ---- layer 2 ----
    gemm_pipe<<<dim3(32, 1), 512, 0, stream>>>(Hbuf2, HDIM, HDIM, W2p, P, (int)PE, 7);
    rnn_rec<<<32, 512, 0, stream>>>(P, W_hh2, b_ih2, b_hh2, Hbuf);

    // ---- FC head ----
    fc_head<<<1, 64, 0, stream>>>(Hbuf, fc_w, fc_b, out);
}